// Round 9
// baseline (928.496 us; speedup 1.0000x reference)
//
#include <hip/hip_runtime.h>

#define L_DIM 128
#define BB 8          // real batch rows per block (padded to 16 for MFMA)

typedef _Float16 f16;
typedef _Float16 f16x8 __attribute__((ext_vector_type(8)));
typedef float f32x4 __attribute__((ext_vector_type(4)));

// tanh(u + b) with bias pre-scaled into the exp2 argument: bk = 2*log2(e)*b.
__device__ __forceinline__ float fast_tanh_b(float x, float bk) {
    float e = __builtin_amdgcn_exp2f(fmaf(x, 2.8853900817779268f, bk));
    float r = __builtin_amdgcn_rcpf(e + 1.0f);
    return fmaf(-2.0f, r, 1.0f);   // large +x -> 1; large -x -> -1
}

// 16 waves @ waves_per_eu(4): unified budget 512/4 = 128 regs/wave.
// Demand ~123 (w2f 64 + acc 16 + af 8 + w1f 8 + misc) -> fits, unlike r2's 64-reg
// disaster. 4 waves/SIMD doubles latency hiding vs r5's 2 (which measured as
// eval-time ~= MFMA-pipe + VALU-pipe fully SERIALIZED).
__attribute__((amdgpu_flat_work_group_size(1024, 1024), amdgpu_waves_per_eu(4)))
__global__ void
cde_kernel(const float* __restrict__ coeffs,
           const float* __restrict__ W_init, const float* __restrict__ b_init,
           const float* __restrict__ W1, const float* __restrict__ b1,
           const float* __restrict__ W2, const float* __restrict__ b2,
           const float* __restrict__ W_out, const float* __restrict__ b_out,
           float* __restrict__ out)
{
    __shared__ __align__(16) f16   z16[16][72];        // fp16 z (rows 8-15 = 0, static)
    __shared__ __align__(16) f16   h16[16][136];       // fp16 hidden activations
    __shared__ __align__(16) float dxT[2][3][16][20];  // [buf][which][c][b]
    __shared__ __align__(16) float zf[BB][64];         // epilogue gather

    const int tid  = threadIdx.x;
    const int blk  = blockIdx.x;
    const int lane = tid & 63;
    const int w    = tid >> 6;        // wave 0..15
    const int q    = lane >> 4;       // quarter-wave 0..3
    const int lr   = lane & 15;
    // GEMM2 split: wave owns 4 hh x 16 c. Col lr of tile tau (0..3):
    //   hh = 4w + (lr&3)   (lane-invariant over tau)
    //   c  = 4*tau + (lr>>2)
    // => c-sum = register accumulate over tau + shfl_xor(4) + shfl_xor(8).
    const int hh   = 4 * w + (lr & 3);
    const int cq   = lr >> 2;
    // After lane-compression this lane owns rows row0, row0+1 (all real):
    const int row0 = (q & 1) * 4 + (q >> 1) * 2;   // q: 0->0, 1->4, 2->2, 3->6

    // ---- one-time: weight fragments into registers ----
    f16x8 w2f[4][4];
    float b2k[4];
#pragma unroll
    for (int tau = 0; tau < 4; ++tau) {
        const int outc = hh * 16 + 4 * tau + cq;
        b2k[tau] = 2.8853900817779268f * b2[outc];
#pragma unroll
        for (int kc = 0; kc < 4; ++kc) {
            const float* src = W2 + (size_t)outc * 128 + kc * 32 + q * 8;
            f16x8 v;
#pragma unroll
            for (int i = 0; i < 8; ++i) v[i] = (f16)src[i];
            w2f[tau][kc] = v;
        }
    }
    f16x8 w1f[2];
    float b1r = 0.f;
    if (w < 8) {
#pragma unroll
        for (int kc = 0; kc < 2; ++kc) {
            const float* src = W1 + (size_t)(w * 16 + lr) * 64 + kc * 32 + q * 8;
            f16x8 v;
#pragma unroll
            for (int i = 0; i < 8; ++i) v[i] = (f16)src[i];
            w1f[kc] = v;
        }
        b1r = b1[w * 16 + lr];
    }

    // ---- init: z0 = X0 @ W_init^T + b_init for (b = row0+j, hh) ----
    float z32r[2], ksumr[2];
#pragma unroll
    for (int j = 0; j < 2; ++j) {
        const float* x0 = coeffs + (size_t)(blk * BB + row0 + j) * (L_DIM - 1) * 64;
        float a = b_init[hh];
#pragma unroll
        for (int c = 0; c < 16; ++c) a = fmaf(x0[c], W_init[hh * 16 + c], a);
        z32r[j] = a;
        ksumr[j] = 0.f;
        if (lr < 4) z16[row0 + j][hh] = (f16)a;   // lr<4 <=> cq==0; hh=4w+lr
    }
    for (int i = tid; i < 8 * 72; i += 1024) z16[8 + i / 72][i % 72] = (f16)0.f;  // pad rows
    if (tid < BB * 16) {   // spline derivs for step 0 -> buffer 0
        const int b = tid >> 4, c = tid & 15;
        const float* seg = coeffs + (size_t)(blk * BB + b) * (L_DIM - 1) * 64;
        float bv = seg[16 + c], cv = seg[32 + c], dv = seg[48 + c];
        dxT[0][0][c][b] = bv;
        dxT[0][1][c][b] = fmaf(0.25f, dv, fmaf(0.5f, cv, bv));
        dxT[0][2][c][b] = seg[64 + 16 + c];
    }
    __syncthreads();

    // ---- main loop: 127 RK4 steps x 4 f-evals, 2 barriers per f-eval ----
    for (int t = 0; t < L_DIM - 1; ++t) {
        const int buf = t & 1;
        float pb = 0.f, pc = 0.f, pd = 0.f, pe = 0.f;   // dxT prefetch (waves 8-9)
#pragma unroll
        for (int s = 0; s < 4; ++s) {
            // Phase A: GEMM1 on waves 0-7; dxT prefetch-loads on waves 8-9 (s==2)
            if (w < 8) {
                f16x8 za0 = *(const f16x8*)&z16[lr][q * 8];
                f16x8 za1 = *(const f16x8*)&z16[lr][32 + q * 8];
                f32x4 hacc = {0.f, 0.f, 0.f, 0.f};
                hacc = __builtin_amdgcn_mfma_f32_16x16x32_f16(za0, w1f[0], hacc, 0, 0, 0);
                hacc = __builtin_amdgcn_mfma_f32_16x16x32_f16(za1, w1f[1], hacc, 0, 0, 0);
#pragma unroll
                for (int r = 0; r < 4; ++r)
                    h16[q * 4 + r][w * 16 + lr] = (f16)fmaxf(hacc[r] + b1r, 0.f);
            } else if (s == 2 && t < L_DIM - 2) {
                const int pt = tid - 512;
                if (pt < BB * 16) {
                    const int b = pt >> 4, c = pt & 15;
                    const float* seg = coeffs + ((size_t)(blk * BB + b) * (L_DIM - 1) + (t + 1)) * 64;
                    pb = seg[16 + c]; pc = seg[32 + c]; pd = seg[48 + c];
                    pe = (t + 1 < L_DIM - 2) ? seg[80 + c] : 0.f;
                }
            }
            __syncthreads();

            // Phase B: 16 MFMAs (4 tiles x 4 K-chunks), b2 folded into tanh;
            // compress -> tanh -> dX-weighted accumulate -> 2-shfl c-sum -> RK4.
            const int ds = (s + 1) >> 1;            // 0,1,1,2
            f32x4 acc[4];
#pragma unroll
            for (int tau = 0; tau < 4; ++tau) acc[tau] = (f32x4){0.f, 0.f, 0.f, 0.f};
#pragma unroll
            for (int kc = 0; kc < 4; ++kc) {
                const f16x8 af = *(const f16x8*)&h16[lr][kc * 32 + q * 8];
#pragma unroll
                for (int tau = 0; tau < 4; ++tau)
                    acc[tau] = __builtin_amdgcn_mfma_f32_16x16x32_f16(af, w2f[tau][kc], acc[tau], 0, 0, 0);
            }
            // Lane-compression: rows 0-7 (real) live in lanes 0-31's 4 regs; move
            // regs 2,3 to lanes 32-63 so all 64 lanes tanh 2 real elements.
            float ka0 = 0.f, ka1 = 0.f;
#pragma unroll
            for (int tau = 0; tau < 4; ++tau) {
                const float2 dvv = *(const float2*)&dxT[buf][ds][4 * tau + cq][row0];
                float u0 = __shfl_xor(acc[tau][2], 32);
                float u1 = __shfl_xor(acc[tau][3], 32);
                float g0 = fast_tanh_b((lane < 32) ? acc[tau][0] : u0, b2k[tau]);
                float g1 = fast_tanh_b((lane < 32) ? acc[tau][1] : u1, b2k[tau]);
                ka0 = fmaf(g0, dvv.x, ka0);
                ka1 = fmaf(g1, dvv.y, ka1);
            }
            // complete the c-sum across the 4 c-quarter lane groups
            ka0 += __shfl_xor(ka0, 4);  ka0 += __shfl_xor(ka0, 8);
            ka1 += __shfl_xor(ka1, 4);  ka1 += __shfl_xor(ka1, 8);
            // RK4 stage update in registers (uniform scalar branches on s)
            float zs0, zs1;
            if (s == 3) {
                z32r[0] = fmaf(ksumr[0] + ka0, 1.f / 6.f, z32r[0]); zs0 = z32r[0];
                z32r[1] = fmaf(ksumr[1] + ka1, 1.f / 6.f, z32r[1]); zs1 = z32r[1];
            } else {
                ksumr[0] = (s == 0) ? ka0 : fmaf(2.f, ka0, ksumr[0]);
                ksumr[1] = (s == 0) ? ka1 : fmaf(2.f, ka1, ksumr[1]);
                const float alpha = (s == 2) ? 1.f : 0.5f;
                zs0 = fmaf(alpha, ka0, z32r[0]);
                zs1 = fmaf(alpha, ka1, z32r[1]);
            }
            if (lr < 4) {
                z16[row0 + 0][hh] = (f16)zs0;
                z16[row0 + 1][hh] = (f16)zs1;
            }
            if (s == 3 && t < L_DIM - 2 && w >= 8) {   // write next-step spline derivs
                const int pt = tid - 512;
                if (pt < BB * 16) {
                    const int b = pt >> 4, c = pt & 15;
                    dxT[buf ^ 1][0][c][b] = pb;
                    dxT[buf ^ 1][1][c][b] = fmaf(0.25f, pd, fmaf(0.5f, pc, pb));
                    dxT[buf ^ 1][2][c][b] = (t + 1 < L_DIM - 2) ? pe : (pb + pc + pd);
                }
            }
            __syncthreads();
        }
    }

    // ---- epilogue: out = zT @ W_out^T + b_out ----
    if (lr < 4) {
        zf[row0 + 0][hh] = z32r[0];
        zf[row0 + 1][hh] = z32r[1];
    }
    __syncthreads();
    if (tid < 64) {
        const int b = lane >> 3, j0 = lane & 7;
        float p = 0.f;
#pragma unroll
        for (int m = 0; m < 8; ++m) p += zf[b][j0 + 8 * m] * W_out[j0 + 8 * m];
        p += __shfl_xor(p, 1, 64);
        p += __shfl_xor(p, 2, 64);
        p += __shfl_xor(p, 4, 64);
        if (j0 == 0) out[blk * BB + b] = p + b_out[0];
    }
}

extern "C" void kernel_launch(void* const* d_in, const int* in_sizes, int n_in,
                              void* d_out, int out_size, void* d_ws, size_t ws_size,
                              hipStream_t stream) {
    const float* coeffs = (const float*)d_in[0];
    const float* W_init = (const float*)d_in[1];
    const float* b_init = (const float*)d_in[2];
    const float* W1     = (const float*)d_in[3];
    const float* b1     = (const float*)d_in[4];
    const float* W2     = (const float*)d_in[5];
    const float* b2     = (const float*)d_in[6];
    const float* W_out  = (const float*)d_in[7];
    const float* b_out  = (const float*)d_in[8];
    cde_kernel<<<256, 1024, 0, stream>>>(coeffs, W_init, b_init, W1, b1, W2, b2,
                                         W_out, b_out, (float*)d_out);
}

// Round 10
// 755.367 us; speedup vs baseline: 1.2292x; 1.2292x over previous
//
#include <hip/hip_runtime.h>

#define L_DIM 128
#define BB 8          // real batch rows per block (padded to 16 for MFMA)

typedef _Float16 f16;
typedef _Float16 f16x8 __attribute__((ext_vector_type(8)));
typedef float f32x4 __attribute__((ext_vector_type(4)));

// tanh(u + b) with bias pre-scaled into the exp2 argument: bk = 2*log2(e)*b.
__device__ __forceinline__ float fast_tanh_b(float x, float bk) {
    float e = __builtin_amdgcn_exp2f(fmaf(x, 2.8853900817779268f, bk));
    float r = __builtin_amdgcn_rcpf(e + 1.0f);
    return fmaf(-2.0f, r, 1.0f);   // large +x -> 1; large -x -> -1
}

// waves_per_eu(2): unified budget 256 regs/wave (128 arch + 128 AGPR for w2f).
// Proven best regime (r5 = 703us). Occupancy pushes (r2/r8/r9) all spill-regressed.
__attribute__((amdgpu_flat_work_group_size(512, 512), amdgpu_waves_per_eu(2)))
__global__ void
cde_kernel(const float* __restrict__ coeffs,
           const float* __restrict__ W_init, const float* __restrict__ b_init,
           const float* __restrict__ W1, const float* __restrict__ b1,
           const float* __restrict__ W2, const float* __restrict__ b2,
           const float* __restrict__ W_out, const float* __restrict__ b_out,
           float* __restrict__ out)
{
    __shared__ __align__(16) f16   z16[16][72];        // fp16 z (rows 8-15 = 0, static)
    __shared__ __align__(16) f16   h16[16][136];       // fp16 hidden activations
    __shared__ __align__(16) float dxT[2][3][16][20];  // [buf][which][c][b]
    __shared__ __align__(16) float zf[BB][64];         // epilogue gather

    const int tid  = threadIdx.x;
    const int blk  = blockIdx.x;
    const int lane = tid & 63;
    const int w    = tid >> 6;        // wave 0..7
    const int q    = lane >> 4;       // quarter-wave 0..3
    const int lr   = lane & 15;
    // GEMM2 column permutation: col lr of tile tau -> outc = hh*16 + c with
    //   hh = w*8 + (lr&7)  (lane-invariant over tau),  c = 2*tau + (lr>>3)
    // => c-sum = register accumulate over tau + ONE shfl_xor(8).
    const int hh   = w * 8 + (lr & 7);
    const int chp  = lr >> 3;
    // After lane-compression this lane owns rows row0, row0+1 (all real):
    const int row0 = (q & 1) * 4 + (q >> 1) * 2;   // q: 0->0, 1->4, 2->2, 3->6

    // ---- one-time: weight fragments into registers ----
    f16x8 w2f[8][4];
    float b2k[8];
#pragma unroll
    for (int t8 = 0; t8 < 8; ++t8) {
        const int outc = hh * 16 + 2 * t8 + chp;
        b2k[t8] = 2.8853900817779268f * b2[outc];
#pragma unroll
        for (int kc = 0; kc < 4; ++kc) {
            const float* src = W2 + (size_t)outc * 128 + kc * 32 + q * 8;
            f16x8 v;
#pragma unroll
            for (int i = 0; i < 8; ++i) v[i] = (f16)src[i];
            w2f[t8][kc] = v;
        }
    }
    f16x8 w1f[2];
#pragma unroll
    for (int kc = 0; kc < 2; ++kc) {
        const float* src = W1 + (size_t)(w * 16 + lr) * 64 + kc * 32 + q * 8;
        f16x8 v;
#pragma unroll
        for (int i = 0; i < 8; ++i) v[i] = (f16)src[i];
        w1f[kc] = v;
    }
    const float b1r = b1[w * 16 + lr];

    // ---- init: z0 = X0 @ W_init^T + b_init for (b = row0+j, hh) ----
    float z32r[2], ksumr[2];
#pragma unroll
    for (int j = 0; j < 2; ++j) {
        const float* x0 = coeffs + (size_t)(blk * BB + row0 + j) * (L_DIM - 1) * 64;
        float a = b_init[hh];
#pragma unroll
        for (int c = 0; c < 16; ++c) a = fmaf(x0[c], W_init[hh * 16 + c], a);
        z32r[j] = a;
        ksumr[j] = 0.f;
        if (lr < 8) z16[row0 + j][hh] = (f16)a;   // lr<8 <=> chp==0; hh=w*8+lr
    }
    for (int i = tid; i < 8 * 72; i += 512) z16[8 + i / 72][i % 72] = (f16)0.f;  // pad rows
    if (tid < BB * 16) {   // spline derivs for step 0 -> buffer 0
        const int b = tid >> 4, c = tid & 15;
        const float* seg = coeffs + (size_t)(blk * BB + b) * (L_DIM - 1) * 64;
        float bv = seg[16 + c], cv = seg[32 + c], dv = seg[48 + c];
        dxT[0][0][c][b] = bv;
        dxT[0][1][c][b] = fmaf(0.25f, dv, fmaf(0.5f, cv, bv));
        dxT[0][2][c][b] = seg[64 + 16 + c];
    }
    __syncthreads();

    // ---- main loop: 127 RK4 steps x 4 f-evals, 2 barriers per f-eval ----
    for (int t = 0; t < L_DIM - 1; ++t) {
        const int buf = t & 1;
        float pb = 0.f, pc = 0.f, pd = 0.f, pe = 0.f;   // dxT prefetch (s1 load, s3 write)
#pragma unroll
        for (int s = 0; s < 4; ++s) {
            // Phase A: GEMM1  h = relu(z @ W1^T + b1)
            {
                f16x8 za0 = *(const f16x8*)&z16[lr][q * 8];
                f16x8 za1 = *(const f16x8*)&z16[lr][32 + q * 8];
                f32x4 hacc = {0.f, 0.f, 0.f, 0.f};
                hacc = __builtin_amdgcn_mfma_f32_16x16x32_f16(za0, w1f[0], hacc, 0, 0, 0);
                hacc = __builtin_amdgcn_mfma_f32_16x16x32_f16(za1, w1f[1], hacc, 0, 0, 0);
#pragma unroll
                for (int r = 0; r < 4; ++r)
                    h16[q * 4 + r][w * 16 + lr] = (f16)fmaxf(hacc[r] + b1r, 0.f);
            }
            __syncthreads();

            // Phase B: two 4-tile passes; odd waves take scheduler priority for
            // their 16-MFMA cluster so their VALU tail overlaps the even waves'
            // MFMA burst (per-SIMD ping-pong; r5's pipes measured fully serial).
            const int ds = (s + 1) >> 1;            // 0,1,1,2
            float ka0 = 0.f, ka1 = 0.f;
#pragma unroll
            for (int hf = 0; hf < 2; ++hf) {
                float2 dvv[4];
#pragma unroll
                for (int tt = 0; tt < 4; ++tt)
                    dvv[tt] = *(const float2*)&dxT[buf][ds][2 * (hf * 4 + tt) + chp][row0];
                f32x4 acc[4];
#pragma unroll
                for (int tt = 0; tt < 4; ++tt)
                    acc[tt] = (f32x4){0.f, 0.f, 0.f, 0.f};
                if (w & 1) __builtin_amdgcn_s_setprio(1);
#pragma unroll
                for (int kc = 0; kc < 4; ++kc) {
                    f16x8 af = *(const f16x8*)&h16[lr][kc * 32 + q * 8];
#pragma unroll
                    for (int tt = 0; tt < 4; ++tt)
                        acc[tt] = __builtin_amdgcn_mfma_f32_16x16x32_f16(af, w2f[hf * 4 + tt][kc], acc[tt], 0, 0, 0);
                }
                if (w & 1) __builtin_amdgcn_s_setprio(0);
                if (hf == 0 && s == 1 && t < L_DIM - 2 && tid < 128) {  // issue next-step loads early
                    const int b = tid >> 4, c = tid & 15;
                    const float* seg = coeffs + ((size_t)(blk * BB + b) * (L_DIM - 1) + (t + 1)) * 64;
                    pb = seg[16 + c]; pc = seg[32 + c]; pd = seg[48 + c];
                    pe = (t + 1 < L_DIM - 2) ? seg[80 + c] : 0.f;
                }
                // Lane-compression: rows 0-7 (real) live in lanes 0-31's 4 regs;
                // move regs 2,3 to lanes 32-63 so all 64 lanes tanh 2 real elements.
#pragma unroll
                for (int tt = 0; tt < 4; ++tt) {
                    float u0 = __shfl_xor(acc[tt][2], 32);
                    float u1 = __shfl_xor(acc[tt][3], 32);
                    float g0 = fast_tanh_b((lane < 32) ? acc[tt][0] : u0, b2k[hf * 4 + tt]);
                    float g1 = fast_tanh_b((lane < 32) ? acc[tt][1] : u1, b2k[hf * 4 + tt]);
                    ka0 = fmaf(g0, dvv[tt].x, ka0);
                    ka1 = fmaf(g1, dvv[tt].y, ka1);
                }
            }
            // complete the c-sum: one shuffle (partner lane lr^8 has other parity)
            ka0 += __shfl_xor(ka0, 8);
            ka1 += __shfl_xor(ka1, 8);
            // RK4 stage update in registers (uniform scalar branches on s)
            float zs0, zs1;
            if (s == 3) {
                z32r[0] = fmaf(ksumr[0] + ka0, 1.f / 6.f, z32r[0]); zs0 = z32r[0];
                z32r[1] = fmaf(ksumr[1] + ka1, 1.f / 6.f, z32r[1]); zs1 = z32r[1];
            } else {
                ksumr[0] = (s == 0) ? ka0 : fmaf(2.f, ka0, ksumr[0]);
                ksumr[1] = (s == 0) ? ka1 : fmaf(2.f, ka1, ksumr[1]);
                const float alpha = (s == 2) ? 1.f : 0.5f;
                zs0 = fmaf(alpha, ka0, z32r[0]);
                zs1 = fmaf(alpha, ka1, z32r[1]);
            }
            if (lr < 8) {
                z16[row0 + 0][hh] = (f16)zs0;
                z16[row0 + 1][hh] = (f16)zs1;
            }
            if (s == 3 && t < L_DIM - 2 && tid < 128) {   // write next-step spline derivs
                const int b = tid >> 4, c = tid & 15;
                dxT[buf ^ 1][0][c][b] = pb;
                dxT[buf ^ 1][1][c][b] = fmaf(0.25f, pd, fmaf(0.5f, pc, pb));
                dxT[buf ^ 1][2][c][b] = (t + 1 < L_DIM - 2) ? pe : (pb + pc + pd);
            }
            __syncthreads();
        }
    }

    // ---- epilogue: out = zT @ W_out^T + b_out ----
    if (lr < 8) {
        zf[row0 + 0][hh] = z32r[0];
        zf[row0 + 1][hh] = z32r[1];
    }
    __syncthreads();
    if (tid < 64) {
        const int b = lane >> 3, j0 = lane & 7;
        float p = 0.f;
#pragma unroll
        for (int m = 0; m < 8; ++m) p += zf[b][j0 + 8 * m] * W_out[j0 + 8 * m];
        p += __shfl_xor(p, 1, 64);
        p += __shfl_xor(p, 2, 64);
        p += __shfl_xor(p, 4, 64);
        if (j0 == 0) out[blk * BB + b] = p + b_out[0];
    }
}

extern "C" void kernel_launch(void* const* d_in, const int* in_sizes, int n_in,
                              void* d_out, int out_size, void* d_ws, size_t ws_size,
                              hipStream_t stream) {
    const float* coeffs = (const float*)d_in[0];
    const float* W_init = (const float*)d_in[1];
    const float* b_init = (const float*)d_in[2];
    const float* W1     = (const float*)d_in[3];
    const float* b1     = (const float*)d_in[4];
    const float* W2     = (const float*)d_in[5];
    const float* b2     = (const float*)d_in[6];
    const float* W_out  = (const float*)d_in[7];
    const float* b_out  = (const float*)d_in[8];
    cde_kernel<<<256, 512, 0, stream>>>(coeffs, W_init, b_init, W1, b1, W2, b2,
                                        W_out, b_out, (float*)d_out);
}